// Round 4
// baseline (230.279 us; speedup 1.0000x reference)
//
#include <hip/hip_runtime.h>

// Problem constants (match reference)
#define N_PTS 32768
#define E_EDGES 524288
#define THREADS 256
#define ROWS_PER_THREAD 2
#define ROWS_PER_BLOCK (THREADS * ROWS_PER_THREAD)   // 512
#define JCHUNK 1024
#define NRB (N_PTS / ROWS_PER_BLOCK)   // 64
#define NJB (N_PTS / JCHUNK)           // 32  -> grid 2048
#define Q_MASK (N_PTS / 2 - 1)         // float4 index mask (16383), keeps prefetch in-bounds

// ws layout: ws[0] = acc_r (double), ws[1] = acc_a (double)

__global__ void init_acc_kernel(double* ws) {
    ws[0] = 0.0;
    ws[1] = 0.0;
}

__global__ __launch_bounds__(256) void attract_kernel(
    const float* __restrict__ emb,
    const float* __restrict__ sparse,
    const int* __restrict__ heads,
    const int* __restrict__ tails,
    double* __restrict__ acc) {
    int tid = blockIdx.x * blockDim.x + threadIdx.x;
    int stride = gridDim.x * blockDim.x;
    float local = 0.0f;
    for (int e = tid; e < E_EDGES; e += stride) {
        int h = heads[e], t = tails[e];
        float2 eh = *reinterpret_cast<const float2*>(emb + 2 * h);
        float2 et = *reinterpret_cast<const float2*>(emb + 2 * t);
        float dx = eh.x - et.x;
        float dy = eh.y - et.y;
        float sqd = fmaf(dx, dx, dy * dy);
        local = fmaf(sparse[e], __log2f(1.0f + sqd), local);
    }
    for (int off = 32; off; off >>= 1) local += __shfl_down(local, off, 64);
    if ((threadIdx.x & 63) == 0) atomicAdd(&acc[1], (double)local);
}

// Repulsive term, difference form (b >= 1 guaranteed in fp, no clamp):
//   b = 1 + dx^2 + dy^2 ; a = fma(b, 1+eps, -1) = s*(1+eps)+eps
//   per 8-group: S += log2(prod a) - log2(prod b)
// 2-deep software pipeline on the uniform J loads (explicit double buffers).
__global__ __launch_bounds__(256) void repulse_kernel(
    const float* __restrict__ emb,
    const float* __restrict__ deg,
    double* __restrict__ acc) {
    int rb = blockIdx.x % NRB;
    int jc = blockIdx.x / NRB;
    int j0 = jc * JCHUNK;

    int i0 = rb * ROWS_PER_BLOCK + threadIdx.x;
    int i1 = i0 + THREADS;
    float2 p0 = *reinterpret_cast<const float2*>(emb + 2 * i0);
    float2 p1 = *reinterpret_cast<const float2*>(emb + 2 * i1);
    float x0 = p0.x, y0 = p0.y, x1 = p1.x, y1 = p1.y;

    const float4* __restrict__ P4 = reinterpret_cast<const float4*>(emb);
    int q = j0 >> 1;   // float4 index of chunk start (2 points per float4)

    float S0 = 0.0f, S1 = 0.0f;

    // prologue: buffer 0 <- groups [0,8)
    float4 A0 = P4[q + 0], B0 = P4[q + 1], C0 = P4[q + 2], D0 = P4[q + 3];

#define COMPUTE(A, B, C, D)                                        \
    {                                                              \
        float pa0 = 1.0f, pb0 = 1.0f, pa1 = 1.0f, pb1 = 1.0f;     \
        _Pragma("unroll")                                          \
        for (int k = 0; k < 4; ++k) {                              \
            float px, py, pz, pw;                                  \
            if (k == 0) { px = A.x; py = A.y; pz = A.z; pw = A.w; }\
            if (k == 1) { px = B.x; py = B.y; pz = B.z; pw = B.w; }\
            if (k == 2) { px = C.x; py = C.y; pz = C.z; pw = C.w; }\
            if (k == 3) { px = D.x; py = D.y; pz = D.z; pw = D.w; }\
            float dxa0 = x0 - px, dya0 = y0 - py;                  \
            float ba0 = fmaf(dxa0, dxa0, fmaf(dya0, dya0, 1.0f));  \
            float aa0 = fmaf(ba0, 1.0001f, -1.0f);                 \
            pa0 *= aa0; pb0 *= ba0;                                \
            float dxa1 = x1 - px, dya1 = y1 - py;                  \
            float ba1 = fmaf(dxa1, dxa1, fmaf(dya1, dya1, 1.0f));  \
            float aa1 = fmaf(ba1, 1.0001f, -1.0f);                 \
            pa1 *= aa1; pb1 *= ba1;                                \
            float dxb0 = x0 - pz, dyb0 = y0 - pw;                  \
            float bb0 = fmaf(dxb0, dxb0, fmaf(dyb0, dyb0, 1.0f));  \
            float ab0 = fmaf(bb0, 1.0001f, -1.0f);                 \
            pa0 *= ab0; pb0 *= bb0;                                \
            float dxb1 = x1 - pz, dyb1 = y1 - pw;                  \
            float bb1 = fmaf(dxb1, dxb1, fmaf(dyb1, dyb1, 1.0f));  \
            float ab1 = fmaf(bb1, 1.0001f, -1.0f);                 \
            pa1 *= ab1; pb1 *= bb1;                                \
        }                                                          \
        S0 += __log2f(pa0) - __log2f(pb0);                         \
        S1 += __log2f(pa1) - __log2f(pb1);                         \
    }

    // main loop: 16 j's per iteration, 2-deep pipelined
    #pragma unroll 1
    for (int jg = 0; jg < JCHUNK; jg += 16) {
        // prefetch buffer 1 <- groups [jg+8, jg+16)
        int qn = (q + 4) & Q_MASK;
        float4 A1 = P4[qn + 0], B1 = P4[qn + 1], C1 = P4[qn + 2], D1 = P4[qn + 3];
        COMPUTE(A0, B0, C0, D0)
        // prefetch buffer 0 <- groups [jg+16, jg+24)  (masked: harmless past end)
        int qm = (q + 8) & Q_MASK;
        A0 = P4[qm + 0]; B0 = P4[qm + 1]; C0 = P4[qm + 2]; D0 = P4[qm + 3];
        COMPUTE(A1, B1, C1, D1)
        q += 8;
    }
#undef COMPUTE

    float contrib = deg[i0] * S0 + deg[i1] * S1;
    for (int off = 32; off; off >>= 1) contrib += __shfl_down(contrib, off, 64);
    if ((threadIdx.x & 63) == 0) atomicAdd(&acc[0], (double)contrib);
}

__global__ void finalize_kernel(const double* __restrict__ acc, float* __restrict__ out) {
    const double LN2 = 0.6931471805599453;
    double acc_r = acc[0];  // sum_i d_i * S_i  (log2 units)
    double acc_a = acc[1];  // sum_e sparse*log2(1+sqd)
    double loss = LN2 * (acc_a - (10.0 / 65536.0) * acc_r);
    out[0] = (float)loss;
}

extern "C" void kernel_launch(void* const* d_in, const int* in_sizes, int n_in,
                              void* d_out, int out_size, void* d_ws, size_t ws_size,
                              hipStream_t stream) {
    const float* emb    = (const float*)d_in[0];
    const float* sparse = (const float*)d_in[1];
    const float* deg    = (const float*)d_in[2];
    const int*   heads  = (const int*)d_in[3];
    const int*   tails  = (const int*)d_in[4];
    float* out = (float*)d_out;
    double* ws = (double*)d_ws;

    hipLaunchKernelGGL(init_acc_kernel, dim3(1), dim3(1), 0, stream, ws);
    hipLaunchKernelGGL(attract_kernel, dim3(512), dim3(256), 0, stream,
                       emb, sparse, heads, tails, ws);
    hipLaunchKernelGGL(repulse_kernel, dim3(NRB * NJB), dim3(256), 0, stream,
                       emb, deg, ws);
    hipLaunchKernelGGL(finalize_kernel, dim3(1), dim3(1), 0, stream, ws, out);
}

// Round 5
// 189.141 us; speedup vs baseline: 1.2175x; 1.2175x over previous
//
#include <hip/hip_runtime.h>

// Problem constants (match reference)
#define N_PTS 32768
#define E_EDGES 524288
#define THREADS 256
#define RPT 8                               // rows per thread (4 packed pairs)
#define ROWS_PER_BLOCK (THREADS * RPT)      // 2048
#define NRB (N_PTS / ROWS_PER_BLOCK)        // 16
#define JCHUNK 256
#define NJB (N_PTS / JCHUNK)                // 128 -> grid 2048

typedef float f32x2 __attribute__((ext_vector_type(2)));

// Packed f32 VOP3P ops (CDNA3/4, gfx90a+). Pure asm (no volatile): results
// are data-flow used, no memory touched -> safe to let the scheduler move.
#define PK_SUB(d, a, b) \
    asm("v_pk_add_f32 %0, %1, %2 neg_lo:[0,1] neg_hi:[0,1]" : "=v"(d) : "v"(a), "v"(b))
#define PK_FMA(d, a, b, c) \
    asm("v_pk_fma_f32 %0, %1, %2, %3" : "=v"(d) : "v"(a), "v"(b), "v"(c))
#define PK_MUL_IP(d, a) \
    asm("v_pk_mul_f32 %0, %0, %1" : "+v"(d) : "v"(a))

// ws layout: ws[0] = acc_r (double), ws[1] = acc_a (double)

__global__ void init_acc_kernel(double* ws) {
    ws[0] = 0.0;
    ws[1] = 0.0;
}

__global__ __launch_bounds__(256) void attract_kernel(
    const float* __restrict__ emb,
    const float* __restrict__ sparse,
    const int* __restrict__ heads,
    const int* __restrict__ tails,
    double* __restrict__ acc) {
    int tid = blockIdx.x * blockDim.x + threadIdx.x;
    int stride = gridDim.x * blockDim.x;
    float local = 0.0f;
    for (int e = tid; e < E_EDGES; e += stride) {
        int h = heads[e], t = tails[e];
        float2 eh = *reinterpret_cast<const float2*>(emb + 2 * h);
        float2 et = *reinterpret_cast<const float2*>(emb + 2 * t);
        float dx = eh.x - et.x;
        float dy = eh.y - et.y;
        float sqd = fmaf(dx, dx, dy * dy);
        local = fmaf(sparse[e], __log2f(1.0f + sqd), local);
    }
    for (int off = 32; off; off >>= 1) local += __shfl_down(local, off, 64);
    if ((threadIdx.x & 63) == 0) atomicAdd(&acc[1], (double)local);
}

// Repulsive term, packed-f32: 2 rows per VGPR pair, difference form
// (per-half math identical to scalar version -> b >= 1 guaranteed, no clamp).
//   b = 1 + dx^2 + dy^2 ; a = fma(b, 1+eps, -1) = s*(1+eps)+eps
//   per row, per 8-j group: S += log2(prod a) - log2(prod b)
__global__ __launch_bounds__(256) void repulse_kernel(
    const float* __restrict__ emb,
    const float* __restrict__ deg,
    double* __restrict__ acc) {
    int rb = blockIdx.x % NRB;
    int jc = blockIdx.x / NRB;
    int j0 = jc * JCHUNK;

    int ibase = rb * ROWS_PER_BLOCK + threadIdx.x;

    // Load 8 rows, pack as 4 x {row2p, row2p+1}
    f32x2 rx[4], ry[4];
    #pragma unroll
    for (int p = 0; p < 4; ++p) {
        float2 pA = *reinterpret_cast<const float2*>(emb + 2 * (ibase + (2 * p + 0) * THREADS));
        float2 pB = *reinterpret_cast<const float2*>(emb + 2 * (ibase + (2 * p + 1) * THREADS));
        rx[p] = (f32x2){pA.x, pB.x};
        ry[p] = (f32x2){pA.y, pB.y};
    }

    const f32x2 ONE2 = {1.0f, 1.0f};
    const f32x2 EPS2 = {1.0001f, 1.0001f};
    const f32x2 M1_2 = {-1.0f, -1.0f};

    float S[8];
    #pragma unroll
    for (int r = 0; r < 8; ++r) S[r] = 0.0f;

    const float4* __restrict__ P4 = reinterpret_cast<const float4*>(emb) + (j0 >> 1);

    for (int g = 0; g < JCHUNK / 8; ++g) {
        float4 A = P4[4 * g + 0];
        float4 B = P4[4 * g + 1];
        float4 C = P4[4 * g + 2];
        float4 D = P4[4 * g + 3];

        f32x2 pa[4], pb[4];
        #pragma unroll
        for (int p = 0; p < 4; ++p) { pa[p] = ONE2; pb[p] = ONE2; }

#define DO_J(xj, yj)                                        \
        {                                                   \
            f32x2 Jx = {(xj), (xj)};                        \
            f32x2 Jy = {(yj), (yj)};                        \
            _Pragma("unroll")                               \
            for (int p = 0; p < 4; ++p) {                   \
                f32x2 dx, dy, t, b, a;                      \
                PK_SUB(dx, rx[p], Jx);                      \
                PK_SUB(dy, ry[p], Jy);                      \
                PK_FMA(t, dy, dy, ONE2);                    \
                PK_FMA(b, dx, dx, t);                       \
                PK_FMA(a, b, EPS2, M1_2);                   \
                PK_MUL_IP(pa[p], a);                        \
                PK_MUL_IP(pb[p], b);                        \
            }                                               \
        }

        DO_J(A.x, A.y) DO_J(A.z, A.w)
        DO_J(B.x, B.y) DO_J(B.z, B.w)
        DO_J(C.x, C.y) DO_J(C.z, C.w)
        DO_J(D.x, D.y) DO_J(D.z, D.w)
#undef DO_J

        #pragma unroll
        for (int p = 0; p < 4; ++p) {
            S[2 * p + 0] += __log2f(pa[p].x) - __log2f(pb[p].x);
            S[2 * p + 1] += __log2f(pa[p].y) - __log2f(pb[p].y);
        }
    }

    float contrib = 0.0f;
    #pragma unroll
    for (int p = 0; p < 4; ++p) {
        contrib = fmaf(deg[ibase + (2 * p + 0) * THREADS], S[2 * p + 0], contrib);
        contrib = fmaf(deg[ibase + (2 * p + 1) * THREADS], S[2 * p + 1], contrib);
    }
    for (int off = 32; off; off >>= 1) contrib += __shfl_down(contrib, off, 64);
    if ((threadIdx.x & 63) == 0) atomicAdd(&acc[0], (double)contrib);
}

__global__ void finalize_kernel(const double* __restrict__ acc, float* __restrict__ out) {
    const double LN2 = 0.6931471805599453;
    double acc_r = acc[0];  // sum_i d_i * S_i  (log2 units)
    double acc_a = acc[1];  // sum_e sparse*log2(1+sqd)
    double loss = LN2 * (acc_a - (10.0 / 65536.0) * acc_r);
    out[0] = (float)loss;
}

extern "C" void kernel_launch(void* const* d_in, const int* in_sizes, int n_in,
                              void* d_out, int out_size, void* d_ws, size_t ws_size,
                              hipStream_t stream) {
    const float* emb    = (const float*)d_in[0];
    const float* sparse = (const float*)d_in[1];
    const float* deg    = (const float*)d_in[2];
    const int*   heads  = (const int*)d_in[3];
    const int*   tails  = (const int*)d_in[4];
    float* out = (float*)d_out;
    double* ws = (double*)d_ws;

    hipLaunchKernelGGL(init_acc_kernel, dim3(1), dim3(1), 0, stream, ws);
    hipLaunchKernelGGL(attract_kernel, dim3(512), dim3(256), 0, stream,
                       emb, sparse, heads, tails, ws);
    hipLaunchKernelGGL(repulse_kernel, dim3(NRB * NJB), dim3(256), 0, stream,
                       emb, deg, ws);
    hipLaunchKernelGGL(finalize_kernel, dim3(1), dim3(1), 0, stream, ws, out);
}

// Round 6
// 177.510 us; speedup vs baseline: 1.2973x; 1.0655x over previous
//
#include <hip/hip_runtime.h>

// Problem constants (match reference)
#define N_PTS 32768
#define E_EDGES 524288
#define THREADS 256
#define RPT 8                                // rows per thread (4 packed pairs)
#define RBLOCK (THREADS * RPT)               // 2048 rows per work item
#define CCHUNK 128                           // j columns per work item
#define NSUP (N_PTS / RBLOCK)                // 16 supertiles per side
#define NWORK 2176                           // sum_{I=0..15} (256 - 16*I)

typedef float f32x2 __attribute__((ext_vector_type(2)));

// Packed f32 VOP3P ops (issue compression: 2 rows per instruction)
#define PK_SUB(d, a, b) \
    asm("v_pk_add_f32 %0, %1, %2 neg_lo:[0,1] neg_hi:[0,1]" : "=v"(d) : "v"(a), "v"(b))
#define PK_FMA(d, a, b, c) \
    asm("v_pk_fma_f32 %0, %1, %2, %3" : "=v"(d) : "v"(a), "v"(b), "v"(c))
#define PK_MUL_IP(d, a) \
    asm("v_pk_mul_f32 %0, %0, %1" : "+v"(d) : "v"(a))

// ws layout: ws[0] = acc_r (double), ws[1] = acc_a (double)

__global__ void init_acc_kernel(double* ws) {
    ws[0] = 0.0;
    ws[1] = 0.0;
}

__global__ __launch_bounds__(256) void attract_kernel(
    const float* __restrict__ emb,
    const float* __restrict__ sparse,
    const int* __restrict__ heads,
    const int* __restrict__ tails,
    double* __restrict__ acc) {
    int tid = blockIdx.x * blockDim.x + threadIdx.x;
    int stride = gridDim.x * blockDim.x;
    float local = 0.0f;
    for (int e = tid; e < E_EDGES; e += stride) {
        int h = heads[e], t = tails[e];
        float2 eh = *reinterpret_cast<const float2*>(emb + 2 * h);
        float2 et = *reinterpret_cast<const float2*>(emb + 2 * t);
        float dx = eh.x - et.x;
        float dy = eh.y - et.y;
        float sqd = fmaf(dx, dx, dy * dy);
        local = fmaf(sparse[e], __log2f(1.0f + sqd), local);
    }
    for (int off = 32; off; off >>= 1) local += __shfl_down(local, off, 64);
    if ((threadIdx.x & 63) == 0) atomicAdd(&acc[1], (double)local);
}

// Repulsive term with triangle symmetry (L_ij = L_ji).
// Work items: 16x16 supertiles of 2048x2048. Strict-upper tiles split into
// 128-wide j-chunks (1920 items, dual row+col accumulation covers (i,j) and
// (j,i)); diagonal supertiles computed full, row-side only (256 items).
// Per pair: b = 1+dx^2+dy^2 (>=1 in fp, no clamp); a = fma(b,1+eps,-1).
// Row chains: per-row product over 8-j group -> 2 logs, weight d_i.
// Col chains (off-diag only): product over thread's 8 rows per j -> 2 logs,
// weight d_j; additive across threads in log domain.
__global__ __launch_bounds__(256) void repulse_kernel(
    const float* __restrict__ emb,
    const float* __restrict__ deg,
    double* __restrict__ acc) {
    // map blockIdx.x -> (I, Jc, diag); block-uniform scalar loop, <=16 iters
    int w = blockIdx.x, I = 0, cnt = 256;
    while (w >= cnt) { w -= cnt; ++I; cnt -= 16; }
    const int Jc = (I << 4) + w;     // j-chunk index in [16*I, 256)
    const bool diag = (w < 16);      // chunk lies in the diagonal supertile

    const int ibase = (I << 11) + threadIdx.x;

    f32x2 rx[4], ry[4];
    #pragma unroll
    for (int p = 0; p < 4; ++p) {
        float2 pA = *reinterpret_cast<const float2*>(emb + 2 * (ibase + (2 * p + 0) * THREADS));
        float2 pB = *reinterpret_cast<const float2*>(emb + 2 * (ibase + (2 * p + 1) * THREADS));
        rx[p] = (f32x2){pA.x, pB.x};
        ry[p] = (f32x2){pA.y, pB.y};
    }

    const f32x2 ONE2 = {1.0f, 1.0f};
    const f32x2 EPS2 = {1.0001f, 1.0001f};
    const f32x2 M1_2 = {-1.0f, -1.0f};

    float S[8];
    #pragma unroll
    for (int r = 0; r < 8; ++r) S[r] = 0.0f;
    float colAcc = 0.0f;

    const float4* __restrict__ P4 = reinterpret_cast<const float4*>(emb) + (Jc << 6);
    const float* __restrict__ djp = deg + (Jc << 7);

// core for one pack p against broadcast (Jx,Jy); FJ = first j of group;
// CM = col mode (0 none, 1 first-pack, 2 accumulate)
#define CORE(p, FJ, CM)                                           \
    {                                                             \
        f32x2 dx_, dy_, t_, b_, a_;                               \
        PK_SUB(dx_, rx[p], Jx);                                   \
        PK_SUB(dy_, ry[p], Jy);                                   \
        PK_FMA(t_, dy_, dy_, ONE2);                               \
        PK_FMA(b_, dx_, dx_, t_);                                 \
        PK_FMA(a_, b_, EPS2, M1_2);                               \
        if (FJ) { pa[p] = a_; pb[p] = b_; }                       \
        else    { PK_MUL_IP(pa[p], a_); PK_MUL_IP(pb[p], b_); }   \
        if (CM == 1) { pc_a = a_; pc_b = b_; }                    \
        if (CM == 2) { PK_MUL_IP(pc_a, a_); PK_MUL_IP(pc_b, b_); }\
    }

#define OFFJ(FJ, xj, yj, dval)                                    \
    {                                                             \
        f32x2 Jx = {(xj), (xj)}, Jy = {(yj), (yj)};               \
        f32x2 pc_a, pc_b;                                         \
        CORE(0, FJ, 1) CORE(1, FJ, 2) CORE(2, FJ, 2) CORE(3, FJ, 2) \
        float qa_ = pc_a.x * pc_a.y;                              \
        float qb_ = pc_b.x * pc_b.y;                              \
        colAcc = fmaf((dval), __log2f(qa_) - __log2f(qb_), colAcc); \
    }

#define DIAJ(FJ, xj, yj)                                          \
    {                                                             \
        f32x2 Jx = {(xj), (xj)}, Jy = {(yj), (yj)};               \
        f32x2 pc_a, pc_b; (void)pc_a; (void)pc_b;                 \
        CORE(0, FJ, 0) CORE(1, FJ, 0) CORE(2, FJ, 0) CORE(3, FJ, 0) \
    }

#define ROWFLUSH                                                  \
    _Pragma("unroll")                                             \
    for (int p = 0; p < 4; ++p) {                                 \
        S[2 * p + 0] += __log2f(pa[p].x) - __log2f(pb[p].x);      \
        S[2 * p + 1] += __log2f(pa[p].y) - __log2f(pb[p].y);      \
    }

    if (!diag) {
        for (int g = 0; g < CCHUNK / 8; ++g) {
            float4 A = P4[4 * g + 0];
            float4 B = P4[4 * g + 1];
            float4 C = P4[4 * g + 2];
            float4 D = P4[4 * g + 3];
            float d0 = djp[8 * g + 0], d1 = djp[8 * g + 1];
            float d2 = djp[8 * g + 2], d3 = djp[8 * g + 3];
            float d4 = djp[8 * g + 4], d5 = djp[8 * g + 5];
            float d6 = djp[8 * g + 6], d7 = djp[8 * g + 7];
            f32x2 pa[4], pb[4];
            OFFJ(1, A.x, A.y, d0) OFFJ(0, A.z, A.w, d1)
            OFFJ(0, B.x, B.y, d2) OFFJ(0, B.z, B.w, d3)
            OFFJ(0, C.x, C.y, d4) OFFJ(0, C.z, C.w, d5)
            OFFJ(0, D.x, D.y, d6) OFFJ(0, D.z, D.w, d7)
            ROWFLUSH
        }
    } else {
        for (int g = 0; g < CCHUNK / 8; ++g) {
            float4 A = P4[4 * g + 0];
            float4 B = P4[4 * g + 1];
            float4 C = P4[4 * g + 2];
            float4 D = P4[4 * g + 3];
            f32x2 pa[4], pb[4];
            DIAJ(1, A.x, A.y) DIAJ(0, A.z, A.w)
            DIAJ(0, B.x, B.y) DIAJ(0, B.z, B.w)
            DIAJ(0, C.x, C.y) DIAJ(0, C.z, C.w)
            DIAJ(0, D.x, D.y) DIAJ(0, D.z, D.w)
            ROWFLUSH
        }
    }
#undef CORE
#undef OFFJ
#undef DIAJ
#undef ROWFLUSH

    float contrib = colAcc;
    #pragma unroll
    for (int p = 0; p < 4; ++p) {
        contrib = fmaf(deg[ibase + (2 * p + 0) * THREADS], S[2 * p + 0], contrib);
        contrib = fmaf(deg[ibase + (2 * p + 1) * THREADS], S[2 * p + 1], contrib);
    }
    for (int off = 32; off; off >>= 1) contrib += __shfl_down(contrib, off, 64);
    if ((threadIdx.x & 63) == 0) atomicAdd(&acc[0], (double)contrib);
}

__global__ void finalize_kernel(const double* __restrict__ acc, float* __restrict__ out) {
    const double LN2 = 0.6931471805599453;
    double acc_r = acc[0];  // sum_ij d_i L_ij  (log2 units)
    double acc_a = acc[1];  // sum_e sparse*log2(1+sqd)
    double loss = LN2 * (acc_a - (10.0 / 65536.0) * acc_r);
    out[0] = (float)loss;
}

extern "C" void kernel_launch(void* const* d_in, const int* in_sizes, int n_in,
                              void* d_out, int out_size, void* d_ws, size_t ws_size,
                              hipStream_t stream) {
    const float* emb    = (const float*)d_in[0];
    const float* sparse = (const float*)d_in[1];
    const float* deg    = (const float*)d_in[2];
    const int*   heads  = (const int*)d_in[3];
    const int*   tails  = (const int*)d_in[4];
    float* out = (float*)d_out;
    double* ws = (double*)d_ws;

    hipLaunchKernelGGL(init_acc_kernel, dim3(1), dim3(1), 0, stream, ws);
    hipLaunchKernelGGL(attract_kernel, dim3(512), dim3(256), 0, stream,
                       emb, sparse, heads, tails, ws);
    hipLaunchKernelGGL(repulse_kernel, dim3(NWORK), dim3(256), 0, stream,
                       emb, deg, ws);
    hipLaunchKernelGGL(finalize_kernel, dim3(1), dim3(1), 0, stream, ws, out);
}

// Round 7
// 114.316 us; speedup vs baseline: 2.0144x; 1.5528x over previous
//
#include <hip/hip_runtime.h>

// Problem constants (match reference)
#define N_PTS 32768
#define E_EDGES 524288
#define THREADS 256
#define RPT 8                                // rows per thread (4 packed pairs)
#define RBLOCK (THREADS * RPT)               // 2048 rows per supertile
#define CCHUNK 32                            // j columns per block (fine-grained for tail util)
#define NB 8704                              // sum_{I=0..15} (1024 - 64*I)
#define EPB 61                               // attract edges per block (61*8704 >= E)
#define NSLOTS 64                            // spread accumulator slots

typedef float f32x2 __attribute__((ext_vector_type(2)));

// Packed f32 VOP3P ops (issue compression: 2 rows per instruction)
#define PK_SUB(d, a, b) \
    asm("v_pk_add_f32 %0, %1, %2 neg_lo:[0,1] neg_hi:[0,1]" : "=v"(d) : "v"(a), "v"(b))
#define PK_FMA(d, a, b, c) \
    asm("v_pk_fma_f32 %0, %1, %2, %3" : "=v"(d) : "v"(a), "v"(b), "v"(c))
#define PK_MUL_IP(d, a) \
    asm("v_pk_mul_f32 %0, %0, %1" : "+v"(d) : "v"(a))

// ws layout: ws[0..63] = acc_r slots, ws[64..127] = acc_a slots (doubles)

__global__ __launch_bounds__(128) void init_acc_kernel(double* ws) {
    ws[threadIdx.x] = 0.0;
}

// Fused kernel: repulsive triangle-dual tile + a 61-edge attract prologue.
//
// Repulsive (L_ij = L_ji): 16 supertiles of 2048 rows; strict-upper j-chunks
// (32 cols) use dual row+col accumulation covering (i,j) and (j,i); diagonal
// supertiles computed full, row-side only.
// Per pair: b = 1+dx^2+dy^2 (>=1 in fp, no clamp); a = fma(b,1+eps,-1).
// Row chains: per-row product over 8-j group -> 2 logs, weight d_i.
// Col chains: product over thread's 8 rows per j -> 2 logs, weight d_j.
__global__ __launch_bounds__(256) void fused_kernel(
    const float* __restrict__ emb,
    const float* __restrict__ deg,
    const float* __restrict__ sparse,
    const int* __restrict__ heads,
    const int* __restrict__ tails,
    double* __restrict__ acc) {
    // ---- attract prologue: one edge per thread (t < EPB) ----
    float aLocal = 0.0f;
    {
        int e = blockIdx.x * EPB + threadIdx.x;
        if (threadIdx.x < EPB && e < E_EDGES) {
            int h = heads[e], t = tails[e];
            float2 eh = *reinterpret_cast<const float2*>(emb + 2 * h);
            float2 et = *reinterpret_cast<const float2*>(emb + 2 * t);
            float dx = eh.x - et.x;
            float dy = eh.y - et.y;
            float sqd = fmaf(dx, dx, dy * dy);
            aLocal = sparse[e] * __log2f(1.0f + sqd);
        }
    }

    // ---- map blockIdx -> (supertile I, chunk w); block-uniform, <=16 iters ----
    int w = blockIdx.x, I = 0, cnt = 1024;
    while (w >= cnt) { w -= cnt; ++I; cnt -= 64; }
    const int JG = (I << 6) + w;     // global 32-col chunk index
    const bool diag = (w < 64);      // chunk inside the diagonal supertile

    const int ibase = (I << 11) + threadIdx.x;

    f32x2 rx[4], ry[4];
    #pragma unroll
    for (int p = 0; p < 4; ++p) {
        float2 pA = *reinterpret_cast<const float2*>(emb + 2 * (ibase + (2 * p + 0) * THREADS));
        float2 pB = *reinterpret_cast<const float2*>(emb + 2 * (ibase + (2 * p + 1) * THREADS));
        rx[p] = (f32x2){pA.x, pB.x};
        ry[p] = (f32x2){pA.y, pB.y};
    }

    const f32x2 ONE2 = {1.0f, 1.0f};
    const f32x2 EPS2 = {1.0001f, 1.0001f};
    const f32x2 M1_2 = {-1.0f, -1.0f};

    float S[8];
    #pragma unroll
    for (int r = 0; r < 8; ++r) S[r] = 0.0f;
    float colAcc = 0.0f;

    const float4* __restrict__ P4 = reinterpret_cast<const float4*>(emb) + (JG << 4);
    const float* __restrict__ djp = deg + (JG << 5);

#define CORE(p, FJ, CM)                                           \
    {                                                             \
        f32x2 dx_, dy_, t_, b_, a_;                               \
        PK_SUB(dx_, rx[p], Jx);                                   \
        PK_SUB(dy_, ry[p], Jy);                                   \
        PK_FMA(t_, dy_, dy_, ONE2);                               \
        PK_FMA(b_, dx_, dx_, t_);                                 \
        PK_FMA(a_, b_, EPS2, M1_2);                               \
        if (FJ) { pa[p] = a_; pb[p] = b_; }                       \
        else    { PK_MUL_IP(pa[p], a_); PK_MUL_IP(pb[p], b_); }   \
        if (CM == 1) { pc_a = a_; pc_b = b_; }                    \
        if (CM == 2) { PK_MUL_IP(pc_a, a_); PK_MUL_IP(pc_b, b_); }\
    }

#define OFFJ(FJ, xj, yj, dval)                                    \
    {                                                             \
        f32x2 Jx = {(xj), (xj)}, Jy = {(yj), (yj)};               \
        f32x2 pc_a, pc_b;                                         \
        CORE(0, FJ, 1) CORE(1, FJ, 2) CORE(2, FJ, 2) CORE(3, FJ, 2) \
        float qa_ = pc_a.x * pc_a.y;                              \
        float qb_ = pc_b.x * pc_b.y;                              \
        colAcc = fmaf((dval), __log2f(qa_) - __log2f(qb_), colAcc); \
    }

#define DIAJ(FJ, xj, yj)                                          \
    {                                                             \
        f32x2 Jx = {(xj), (xj)}, Jy = {(yj), (yj)};               \
        f32x2 pc_a, pc_b; (void)pc_a; (void)pc_b;                 \
        CORE(0, FJ, 0) CORE(1, FJ, 0) CORE(2, FJ, 0) CORE(3, FJ, 0) \
    }

#define ROWFLUSH                                                  \
    _Pragma("unroll")                                             \
    for (int p = 0; p < 4; ++p) {                                 \
        S[2 * p + 0] += __log2f(pa[p].x) - __log2f(pb[p].x);      \
        S[2 * p + 1] += __log2f(pa[p].y) - __log2f(pb[p].y);      \
    }

    if (!diag) {
        #pragma unroll
        for (int g = 0; g < CCHUNK / 8; ++g) {
            float4 A = P4[4 * g + 0];
            float4 B = P4[4 * g + 1];
            float4 C = P4[4 * g + 2];
            float4 D = P4[4 * g + 3];
            float d0 = djp[8 * g + 0], d1 = djp[8 * g + 1];
            float d2 = djp[8 * g + 2], d3 = djp[8 * g + 3];
            float d4 = djp[8 * g + 4], d5 = djp[8 * g + 5];
            float d6 = djp[8 * g + 6], d7 = djp[8 * g + 7];
            f32x2 pa[4], pb[4];
            OFFJ(1, A.x, A.y, d0) OFFJ(0, A.z, A.w, d1)
            OFFJ(0, B.x, B.y, d2) OFFJ(0, B.z, B.w, d3)
            OFFJ(0, C.x, C.y, d4) OFFJ(0, C.z, C.w, d5)
            OFFJ(0, D.x, D.y, d6) OFFJ(0, D.z, D.w, d7)
            ROWFLUSH
        }
    } else {
        #pragma unroll
        for (int g = 0; g < CCHUNK / 8; ++g) {
            float4 A = P4[4 * g + 0];
            float4 B = P4[4 * g + 1];
            float4 C = P4[4 * g + 2];
            float4 D = P4[4 * g + 3];
            f32x2 pa[4], pb[4];
            DIAJ(1, A.x, A.y) DIAJ(0, A.z, A.w)
            DIAJ(0, B.x, B.y) DIAJ(0, B.z, B.w)
            DIAJ(0, C.x, C.y) DIAJ(0, C.z, C.w)
            DIAJ(0, D.x, D.y) DIAJ(0, D.z, D.w)
            ROWFLUSH
        }
    }
#undef CORE
#undef OFFJ
#undef DIAJ
#undef ROWFLUSH

    float contrib = colAcc;
    #pragma unroll
    for (int p = 0; p < 4; ++p) {
        contrib = fmaf(deg[ibase + (2 * p + 0) * THREADS], S[2 * p + 0], contrib);
        contrib = fmaf(deg[ibase + (2 * p + 1) * THREADS], S[2 * p + 1], contrib);
    }
    for (int off = 32; off; off >>= 1) {
        contrib += __shfl_down(contrib, off, 64);
        aLocal  += __shfl_down(aLocal,  off, 64);
    }
    if ((threadIdx.x & 63) == 0) {
        int slot = blockIdx.x & (NSLOTS - 1);
        atomicAdd(&acc[slot], (double)contrib);
        atomicAdd(&acc[NSLOTS + slot], (double)aLocal);
    }
}

__global__ void finalize_kernel(const double* __restrict__ acc, float* __restrict__ out) {
    const double LN2 = 0.6931471805599453;
    double acc_r = 0.0, acc_a = 0.0;
    for (int s = 0; s < NSLOTS; ++s) { acc_r += acc[s]; acc_a += acc[NSLOTS + s]; }
    double loss = LN2 * (acc_a - (10.0 / 65536.0) * acc_r);
    out[0] = (float)loss;
}

extern "C" void kernel_launch(void* const* d_in, const int* in_sizes, int n_in,
                              void* d_out, int out_size, void* d_ws, size_t ws_size,
                              hipStream_t stream) {
    const float* emb    = (const float*)d_in[0];
    const float* sparse = (const float*)d_in[1];
    const float* deg    = (const float*)d_in[2];
    const int*   heads  = (const int*)d_in[3];
    const int*   tails  = (const int*)d_in[4];
    float* out = (float*)d_out;
    double* ws = (double*)d_ws;

    hipLaunchKernelGGL(init_acc_kernel, dim3(1), dim3(128), 0, stream, ws);
    hipLaunchKernelGGL(fused_kernel, dim3(NB), dim3(256), 0, stream,
                       emb, deg, sparse, heads, tails, ws);
    hipLaunchKernelGGL(finalize_kernel, dim3(1), dim3(1), 0, stream, ws, out);
}